// Round 6
// baseline (785.123 us; speedup 1.0000x reference)
//
#include <hip/hip_runtime.h>
#include <hip/hip_bf16.h>

// Problem dims
#define V    50257
#define VPAD 50304          // padded vocab rows for clean 128-tiles (393*128)
#define DD   128
#define HH   256
#define G3   768            // 3*H
#define BB   16
#define TT   128

typedef _Float16 h2   __attribute__((ext_vector_type(2)));
typedef _Float16 h8   __attribute__((ext_vector_type(8)));
typedef short  bf16x8 __attribute__((ext_vector_type(8)));
typedef float  f32x4  __attribute__((ext_vector_type(4)));

typedef __attribute__((address_space(3))) uint4* lds_u4_t;
typedef const __attribute__((address_space(1))) uint4* gbl_u4_t;

__device__ __forceinline__ void async_copy16(const uint4* g, uint4* lds_base) {
    // LDS dest = wave-uniform base + lane*16 (per-lane global scatter is OK)
    __builtin_amdgcn_global_load_lds((gbl_u4_t)g, (lds_u4_t)lds_base, 16, 0, 0);
}

#if __has_builtin(__builtin_amdgcn_fdot2)
#define USE_FDOT2 1
#else
#define USE_FDOT2 0
#endif

__device__ __forceinline__ float sigmoid_(float x) { return 1.0f / (1.0f + __expf(-x)); }
__device__ __forceinline__ float tanh_(float x)    { float e = __expf(2.0f * x); return (e - 1.0f) / (e + 1.0f); }

__device__ __forceinline__ float fdot2_(h2 a, h2 b, float c) {
#if USE_FDOT2
    return __builtin_amdgcn_fdot2(a, b, c, false);
#else
    return c + (float)a.x * (float)b.x + (float)a.y * (float)b.y;
#endif
}

// ---------------------------------------------------------------------------
// Kernel P (merged): blocks [0,256): x = embed[ids]; gx = x @ W_ih^T + b_ih
//                    blocks [256,6544): convert W_out fp32 -> bf16 padded
// ---------------------------------------------------------------------------
__global__ __launch_bounds__(256) void k_prep(
    const int* __restrict__ ids, const float* __restrict__ embed,
    const float* __restrict__ W_ih, const float* __restrict__ b_ih,
    float* __restrict__ gx,
    const float* __restrict__ Wout, __hip_bfloat16* __restrict__ Wb)
{
    __shared__ float xs[8][DD];
    const int tid = threadIdx.x;

    if (blockIdx.x >= 256) {
        // ---- W_out conversion path ----
        long base = ((long)(blockIdx.x - 256) * 256 + tid) * 8;
        const long VALID = (long)V * HH;   // 12,865,792 (divisible by 8)
        union { __hip_bfloat16 b[8]; uint4 u; } pk;
        if (base < VALID) {
            float4 f0 = ((const float4*)Wout)[base / 4];
            float4 f1 = ((const float4*)Wout)[base / 4 + 1];
            pk.b[0] = __float2bfloat16(f0.x); pk.b[1] = __float2bfloat16(f0.y);
            pk.b[2] = __float2bfloat16(f0.z); pk.b[3] = __float2bfloat16(f0.w);
            pk.b[4] = __float2bfloat16(f1.x); pk.b[5] = __float2bfloat16(f1.y);
            pk.b[6] = __float2bfloat16(f1.z); pk.b[7] = __float2bfloat16(f1.w);
        } else {
            pk.u = make_uint4(0, 0, 0, 0);
        }
        *(uint4*)(Wb + base) = pk.u;
        return;
    }

    // ---- embed + gx path ----
    const int row0 = blockIdx.x * 8;

#pragma unroll
    for (int i = 0; i < 4; ++i) {
        int e = tid + i * 256;
        int r = e >> 7, k = e & 127;
        int id = ids[row0 + r];
        xs[r][k] = embed[(long)id * DD + k];
    }
    __syncthreads();

#pragma unroll
    for (int o = 0; o < 3; ++o) {
        int j = tid + o * 256;
        float bias = b_ih[j];
        float acc[8];
#pragma unroll
        for (int r = 0; r < 8; ++r) acc[r] = bias;
        const float4* wrow = (const float4*)(W_ih + (long)j * DD);
        for (int q = 0; q < 32; ++q) {
            float4 w = wrow[q];
#pragma unroll
            for (int r = 0; r < 8; ++r) {
                acc[r] += w.x * xs[r][q * 4 + 0] + w.y * xs[r][q * 4 + 1]
                        + w.z * xs[r][q * 4 + 2] + w.w * xs[r][q * 4 + 3];
            }
        }
#pragma unroll
        for (int r = 0; r < 8; ++r) gx[(long)(row0 + r) * G3 + j] = acc[r];
    }
}

// ---------------------------------------------------------------------------
// Kernel G: GRU recurrence. ROUND-6 FIX: remove per-step global stores from
// the critical path.
// Evidence chain: two radically different designs (512-thr/192-reg/1-barrier
// vs 768-thr/128-reg/2-barrier, 3x the LDS instrs) give IDENTICAL ~3400
// cyc/step -> registers/spill/LDS/barrier-count/VALU are all ruled out.
// The invariant: every step issues a global_store (hout) right before a
// __syncthreads(). The compiler emits s_waitcnt vmcnt(0) before s_barrier,
// and vmcnt counts stores until WRITE-ACK -> every step serializes a
// ~500-1000cyc store round-trip (write-miss on poisoned memory) into the
// recurrence. Fix: stage hout in a 64KB LDS buffer, flush once at the end.
// ---------------------------------------------------------------------------
__global__ __launch_bounds__(768)
__attribute__((amdgpu_waves_per_eu(3, 3)))
void k_gru(
    const float* __restrict__ gx, const float* __restrict__ W_hh,
    const float* __restrict__ b_hh, __hip_bfloat16* __restrict__ hout)
{
    __shared__ _Float16      hhs[HH];        // current hidden state (f16)
    __shared__ float         ghs[G3];        // per-step gate pre-activations
    __shared__ unsigned short hbuf[TT][HH];  // 64KB staged bf16 output

    const int j = threadIdx.x;      // [0,768) = W_hh row
    const int b = blockIdx.x;       // batch

    // one-time: this thread's full W_hh row -> 128 h2 regs.
    h2 w[128];
    const float4* wr = (const float4*)(W_hh + (long)j * HH);
#pragma unroll
    for (int qq = 0; qq < 8; ++qq) {
        float4 f[8];
#pragma unroll
        for (int q = 0; q < 8; ++q) f[q] = wr[qq * 8 + q];
        asm volatile("" ::: "memory");
#pragma unroll
        for (int q = 0; q < 8; ++q) {
            w[qq * 16 + 2 * q]     = h2{(_Float16)f[q].x, (_Float16)f[q].y};
            w[qq * 16 + 2 * q + 1] = h2{(_Float16)f[q].z, (_Float16)f[q].w};
        }
    }
    const float bias = b_hh[j];

    if (j < HH) hhs[j] = (_Float16)0.0f;
    __syncthreads();

    const float* gxb = gx + (long)b * TT * G3;
    float hold = 0.0f;

    for (int t = 0; t < TT; ++t) {
        // gx loads issued at step top; ~700-cycle dot phase hides them
        float xr = 0.f, xz = 0.f, xn = 0.f;
        if (j < HH) {
            const float* row = gxb + (long)t * G3;
            xr = row[j]; xz = row[HH + j]; xn = row[2 * HH + j];
        }

        // dot(W[j], h): 32 b128 broadcast reads, chunked 4-at-a-time
        float da = 0.f, db = 0.f;
        const h8* hp8 = (const h8*)hhs;
#pragma unroll
        for (int cc = 0; cc < 8; ++cc) {
            h8 hv0 = hp8[cc * 4 + 0];
            h8 hv1 = hp8[cc * 4 + 1];
            h8 hv2 = hp8[cc * 4 + 2];
            h8 hv3 = hp8[cc * 4 + 3];
            asm volatile("" ::: "memory");
            const h8 hvs[4] = {hv0, hv1, hv2, hv3};
#pragma unroll
            for (int c2 = 0; c2 < 4; ++c2) {
                const h2* hp = (const h2*)&hvs[c2];
#pragma unroll
                for (int jj = 0; jj < 4; ++jj) {
                    int p = cc * 16 + c2 * 4 + jj;
                    if (jj & 1) db = fdot2_(w[p], hp[jj], db);
                    else        da = fdot2_(w[p], hp[jj], da);
                }
            }
        }
        ghs[j] = da + db + bias;
        __syncthreads();            // ghs ready; all hhs reads drained (DS only)

        if (j < HH) {
            float r = sigmoid_(xr + ghs[j]);
            float z = sigmoid_(xz + ghs[HH + j]);
            float n = tanh_(xn + r * ghs[2 * HH + j]);
            float hnew = (1.0f - z) * n + z * hold;
            hold = hnew;
            hhs[j] = (_Float16)hnew;
            union { __hip_bfloat16 bb; unsigned short u; } cv;
            cv.bb = __float2bfloat16(hnew);
            hbuf[t][j] = cv.u;      // LDS staging, NOT a global store
        }
        __syncthreads();            // hhs[t+1] ready; DS-only drain
    }

    // single bulk flush: 64KB contiguous per block, coalesced uint4 stores
    __syncthreads();
    const uint4* src = (const uint4*)hbuf;
    uint4* dst = (uint4*)(hout + (long)b * TT * HH);
#pragma unroll 2
    for (int i2 = j; i2 < TT * HH / 8; i2 += 768) dst[i2] = src[i2];
}

// ---------------------------------------------------------------------------
// Kernel C: LM head GEMM. C[2048,50257] = A[2048,256] * B[50304,256]^T, bf16
// MFMA 16x16x32, BM=BN=128, BK=64, 256 threads (4 waves, 2x2 of 64x64).
// (round-3 configuration: XCD-aligned 1-D grid; measured H ~= 165us)
// ---------------------------------------------------------------------------
__global__ __launch_bounds__(256) void k_head(
    const __hip_bfloat16* __restrict__ Ah, const __hip_bfloat16* __restrict__ Bw,
    float* __restrict__ out)
{
    __shared__ unsigned short As[128 * 64];
    __shared__ unsigned short Bs[128 * 64];
    const int i    = threadIdx.x;
    const int wave = i >> 6, lane = i & 63;
    const int quad = lane >> 4, mr = lane & 15;

    // XCD-aligned tile assignment: lid%8 == ntile%8 (bijective over valid tiles)
    const int lid = blockIdx.x;          // [0, 6400)
    const int xq  = lid & 7;
    const int j   = lid >> 3;            // [0, 800)
    const int nt  = xq + 8 * (j % 50);   // n-tile, nt%8 == lid%8
    if (nt >= 393) return;               // 112 pad blocks idle
    const int m0  = (j / 50) * 128;
    const int n0  = nt * 128;

    const int wm0  = (wave >> 1) * 64;
    const int wn0  = (wave & 1) * 64;

    f32x4 acc[4][4];
#pragma unroll
    for (int a = 0; a < 4; ++a)
#pragma unroll
        for (int c = 0; c < 4; ++c) acc[a][c] = (f32x4){0.f, 0.f, 0.f, 0.f};

    const uint4* Ag = (const uint4*)Ah;   // row = 32 uint4 (256 bf16)
    const uint4* Bg = (const uint4*)Bw;
    uint4* Asv = (uint4*)As;
    uint4* Bsv = (uint4*)Bs;

    // Precompute per-lane global base addresses + wave-uniform LDS bases.
    // Segment seg = c*4 + wave covers LDS slots [seg*64, seg*64+64).
    const uint4* agp[4]; const uint4* bgp[4];
    uint4* alds[4]; uint4* blds[4];
#pragma unroll
    for (int c = 0; c < 4; ++c) {
        int seg   = c * 4 + wave;
        int row   = seg * 8 + (lane >> 3);
        int chunk = (lane & 7) ^ (row & 7);
        agp[c] = Ag + (long)(m0 + row) * 32 + chunk;
        bgp[c] = Bg + (long)(n0 + row) * 32 + chunk;
        alds[c] = Asv + seg * 64;   // + lane*16B implicit in global_load_lds
        blds[c] = Bsv + seg * 64;
    }

    for (int ks = 0; ks < 4; ++ks) {
        __syncthreads();   // previous iteration's LDS readers done
#pragma unroll
        for (int c = 0; c < 4; ++c) async_copy16(agp[c] + ks * 8, alds[c]);
#pragma unroll
        for (int c = 0; c < 4; ++c) async_copy16(bgp[c] + ks * 8, blds[c]);
        __syncthreads();   // compiler emits s_waitcnt vmcnt(0) before barrier

#pragma unroll
        for (int kk = 0; kk < 2; ++kk) {
            bf16x8 af[4], bf[4];
#pragma unroll
            for (int wmi = 0; wmi < 4; ++wmi) {
                int row  = wm0 + wmi * 16 + mr;
                int slot = (kk * 4 + quad) ^ (row & 7);
                af[wmi] = *(const bf16x8*)&As[(row * 8 + slot) * 8];
            }
#pragma unroll
            for (int wni = 0; wni < 4; ++wni) {
                int row  = wn0 + wni * 16 + mr;
                int slot = (kk * 4 + quad) ^ (row & 7);
                bf[wni] = *(const bf16x8*)&Bs[(row * 8 + slot) * 8];
            }
#pragma unroll
            for (int wmi = 0; wmi < 4; ++wmi)
#pragma unroll
                for (int wni = 0; wni < 4; ++wni)
                    acc[wmi][wni] = __builtin_amdgcn_mfma_f32_16x16x32_bf16(
                        af[wmi], bf[wni], acc[wmi][wni], 0, 0, 0);
        }
    }

    // epilogue: C/D layout col = lane&15, row = quad*4 + reg
#pragma unroll
    for (int wmi = 0; wmi < 4; ++wmi) {
#pragma unroll
        for (int rr = 0; rr < 4; ++rr) {
            long m = m0 + wm0 + wmi * 16 + quad * 4 + rr;
            float* orow = out + m * (long)V;
#pragma unroll
            for (int wni = 0; wni < 4; ++wni) {
                int n = n0 + wn0 + wni * 16 + mr;
                if (n < V) orow[n] = acc[wmi][wni][rr];
            }
        }
    }
}

// ---------------------------------------------------------------------------
extern "C" void kernel_launch(void* const* d_in, const int* in_sizes, int n_in,
                              void* d_out, int out_size, void* d_ws, size_t ws_size,
                              hipStream_t stream) {
    const int*   ids   = (const int*)d_in[0];
    const float* embed = (const float*)d_in[1];
    const float* W_ih  = (const float*)d_in[2];
    const float* b_ih  = (const float*)d_in[3];
    const float* W_hh  = (const float*)d_in[4];
    const float* b_hh  = (const float*)d_in[5];
    const float* W_out = (const float*)d_in[6];
    float* out = (float*)d_out;

    // workspace layout (ws re-poisoned each launch; everything rewritten here)
    char* ws = (char*)d_ws;
    float*          gx  = (float*)ws;                           // 2048*768*4   = 6,291,456 B
    __hip_bfloat16* hbf = (__hip_bfloat16*)(ws + 6291456);      // 2048*256*2   = 1,048,576 B
    __hip_bfloat16* wbf = (__hip_bfloat16*)(ws + 7340032);      // 50304*256*2  = 25,755,648 B

    k_prep<<<6544, 256, 0, stream>>>(ids, embed, W_ih, b_ih, gx, W_out, wbf);
    k_gru<<<16, 768, 0, stream>>>(gx, W_hh, b_hh, hbf);
    k_head<<<6400, 256, 0, stream>>>(hbf, wbf, out);
}